// Round 3
// baseline (484.899 us; speedup 1.0000x reference)
//
#include <hip/hip_runtime.h>

#define B_    256
#define N_    256
#define DIN   768
#define DOUT  300
#define DOUTP 320           // padded to 20*16
#define M_    (B_*N_)       // 65536
#define HP_ELEMS (M_*DOUT)  // 19660800
#define NEG_INF -9.0e15f

typedef _Float16 f16;
typedef __attribute__((ext_vector_type(8))) _Float16 f16x8;
typedef __attribute__((ext_vector_type(4))) _Float16 f16x4;
typedef __attribute__((ext_vector_type(4))) float    f32x4;

__device__ __forceinline__ void async_copy16(void* lds, const void* g) {
    __builtin_amdgcn_global_load_lds(
        (const __attribute__((address_space(1))) void*)g,
        (__attribute__((address_space(3))) void*)lds, 16, 0, 0);
}

__device__ __forceinline__ f16x8 cvt8(float4 u, float4 v) {
    return (f16x8){(f16)u.x,(f16)u.y,(f16)u.z,(f16)u.w,
                   (f16)v.x,(f16)v.y,(f16)v.z,(f16)v.w};
}

// ---------------- kernel 0: Wt[n][k] = f16(W[k][n]), zero-pad n>=300 -------
__global__ __launch_bounds__(256) void prep_wt(const float* __restrict__ W,
                                               f16* __restrict__ Wt) {
    int idx = blockIdx.x * 256 + threadIdx.x;
    if (idx >= DOUTP * DIN) return;
    int n = idx / DIN, k = idx - n * DIN;
    float v = (n < DOUT) ? W[k * DOUT + n] : 0.0f;
    Wt[idx] = (f16)v;
}

// ---------------- kernel 1: Wh = h@W + pos; f_src/f_dst; WhT fp16 to ws ----
// grid 1024 (64 rows/block), 256 threads. Wave: (w&1)*32 rows x (w>>1)*160 cols.
// A-fragments register-direct from h (no LDS); B double-buffered async DMA
// issued at iteration top (in flight across the MFMA body).
__global__ __launch_bounds__(256, 3) void gemm1(
    const float* __restrict__ h, const f16* __restrict__ Wt,
    const int* __restrict__ positions,
    const float* __restrict__ a_src, const float* __restrict__ a_dst,
    const float* __restrict__ pos_table,
    f16* __restrict__ WhT, float* __restrict__ f_src, float* __restrict__ f_dst)
{
    __shared__ f16 Bl[2][DOUTP * 32];    // 2 x 20480 B
    __shared__ float pfs[64][2], pfd[64][2];

    const int tid  = threadIdx.x;
    const int wave = tid >> 6, lane = tid & 63;
    const int quad = lane >> 4, c = lane & 15;
    const int rh = wave & 1, chf = wave >> 1;
    const int rowbase = blockIdx.x * 64;

    const int brow = lane >> 2;
    const int bj   = (lane & 3) ^ (brow & 3);

    const float* hrow0 = h + (size_t)(rowbase + rh * 32 + c) * DIN + quad * 8;
    const float* hrow1 = hrow0 + 16 * DIN;

    float4 a[3][4];

#define LOAD_A(set, kt) do { \
    const float4* p0 = (const float4*)(hrow0 + (kt) * 32); \
    const float4* p1 = (const float4*)(hrow1 + (kt) * 32); \
    a[set][0] = p0[0]; a[set][1] = p0[1]; \
    a[set][2] = p1[0]; a[set][3] = p1[1]; } while (0)

#define DMA_B(buf, kt) do { \
    _Pragma("unroll") \
    for (int i_ = 0; i_ < 5; ++i_) { \
        int chk_ = wave + 4 * i_; \
        int n_ = chk_ * 16 + brow; \
        async_copy16((char*)Bl[buf] + chk_ * 1024, \
                     Wt + (size_t)n_ * DIN + (kt) * 32 + bj * 8); \
    } } while (0)

    f32x4 acc[2][10];
#pragma unroll
    for (int rt = 0; rt < 2; ++rt)
#pragma unroll
        for (int i = 0; i < 10; ++i) acc[rt][i] = (f32x4){0.f, 0.f, 0.f, 0.f};

    LOAD_A(0, 0); LOAD_A(1, 1);
    DMA_B(0, 0);  DMA_B(1, 1);
    __syncthreads();

#pragma unroll
    for (int kt = 0; kt < 24; ++kt) {
        const int cur = kt & 1;
        // issues at iteration top: in flight across this iteration's body
        if (kt >= 1 && kt + 1 < 24) DMA_B(cur ^ 1, kt + 1);
        if (kt + 2 < 24) LOAD_A((kt + 2) % 3, kt + 2);

        f16x8 af0 = cvt8(a[kt % 3][0], a[kt % 3][1]);
        f16x8 af1 = cvt8(a[kt % 3][2], a[kt % 3][3]);
#pragma unroll
        for (int i = 0; i < 10; ++i) {
            int n = (chf * 10 + i) * 16 + c;
            f16x8 bf = *(const f16x8*)&Bl[cur][n * 32 + (quad ^ (n & 3)) * 8];
            acc[0][i] = __builtin_amdgcn_mfma_f32_16x16x32_f16(af0, bf, acc[0][i], 0, 0, 0);
            acc[1][i] = __builtin_amdgcn_mfma_f32_16x16x32_f16(af1, bf, acc[1][i], 0, 0, 0);
        }
        __syncthreads();
    }

    // ---- epilogue ----
    const int bidx = rowbase >> 8;
    const int mloc = rowbase & 255;

    int posr[2][4];
#pragma unroll
    for (int rt = 0; rt < 2; ++rt)
#pragma unroll
        for (int r = 0; r < 4; ++r)
            posr[rt][r] = positions[rowbase + rh * 32 + rt * 16 + quad * 4 + r];

    float fs[2][4] = {{0,0,0,0},{0,0,0,0}}, fd[2][4] = {{0,0,0,0},{0,0,0,0}};
#pragma unroll
    for (int i = 0; i < 10; ++i) {
        int col = (chf * 10 + i) * 16 + c;
        if (col < DOUT) {
            float as = a_src[col], ad = a_dst[col];
#pragma unroll
            for (int rt = 0; rt < 2; ++rt)
#pragma unroll
                for (int r = 0; r < 4; ++r) {
                    float v = acc[rt][i][r] + pos_table[posr[rt][r] * DOUT + col];
                    acc[rt][i][r] = v;
                    fs[rt][r] += v * as;
                    fd[rt][r] += v * ad;
                }
        } else {
#pragma unroll
            for (int rt = 0; rt < 2; ++rt)
#pragma unroll
                for (int r = 0; r < 4; ++r) acc[rt][i][r] = 0.0f;
        }
    }
#pragma unroll
    for (int off = 1; off < 16; off <<= 1) {
#pragma unroll
        for (int rt = 0; rt < 2; ++rt)
#pragma unroll
            for (int r = 0; r < 4; ++r) {
                fs[rt][r] += __shfl_xor(fs[rt][r], off, 16);
                fd[rt][r] += __shfl_xor(fd[rt][r], off, 16);
            }
    }
    if (c == 0) {
#pragma unroll
        for (int rt = 0; rt < 2; ++rt)
#pragma unroll
            for (int r = 0; r < 4; ++r) {
                int row = rh * 32 + rt * 16 + quad * 4 + r;
                pfs[row][chf] = fs[rt][r];
                pfd[row][chf] = fd[rt][r];
            }
    }
#pragma unroll
    for (int i = 0; i < 10; ++i) {
        int col = (chf * 10 + i) * 16 + c;
#pragma unroll
        for (int rt = 0; rt < 2; ++rt) {
            int mrow = mloc + rh * 32 + rt * 16 + quad * 4;
            f16x4 u = (f16x4){(f16)acc[rt][i][0], (f16)acc[rt][i][1],
                              (f16)acc[rt][i][2], (f16)acc[rt][i][3]};
            *(f16x4*)(WhT + ((size_t)bidx * DOUTP + col) * N_ + mrow) = u;
        }
    }
    __syncthreads();
    if (tid < 64) {
        f_src[rowbase + tid] = pfs[tid][0] + pfs[tid][1];
        f_dst[rowbase + tid] = pfd[tid][0] + pfd[tid][1];
    }
#undef LOAD_A
#undef DMA_B
}

// -------- kernel 2: fused masked-softmax + h_prime = att @ Wh --------------
// grid 1024 (64 rows/block). Phase 1: compute att rows in-register, write to
// d_out AND f16 into LDS A-tile. Phase 2: MFMA K-loop over WhT, B pipelined.
__global__ __launch_bounds__(256, 2) void gemm2(
    const float* __restrict__ adj, const float* __restrict__ f_src,
    const float* __restrict__ f_dst, const f16* __restrict__ WhT,
    float* __restrict__ att, float* __restrict__ hp)
{
    __shared__ f16 Al[64 * 264];         // 33792 B (stride 264: +8 pad)
    __shared__ f16 Bl[2][DOUTP * 32];    // 40960 B

    const int tid  = threadIdx.x;
    const int wave = tid >> 6, lane = tid & 63;
    const int quad = lane >> 4, c = lane & 15;
    const int rh = wave & 1, chf = wave >> 1;
    const int rowbase = blockIdx.x * 64;
    const int bidx = rowbase >> 8;

    const int brow = lane >> 2;
    const int bj   = (lane & 3) ^ (brow & 3);

#define DMA_B2(buf, kt) do { \
    _Pragma("unroll") \
    for (int i_ = 0; i_ < 5; ++i_) { \
        int chk_ = wave + 4 * i_; \
        int n_ = chk_ * 16 + brow; \
        async_copy16((char*)Bl[buf] + chk_ * 1024, \
                     WhT + ((size_t)bidx * DOUTP + n_) * N_ + (kt) * 32 + bj * 8); \
    } } while (0)

    // issue first two B tiles immediately: latency hides behind phase 1
    DMA_B2(0, 0);
    DMA_B2(1, 1);

    // ---- phase 1: softmax for 64 rows (wave: 4 groups of 4 rows) ----
    const int sub = lane >> 4, l16 = lane & 15;

    float4 fdv[4];
#pragma unroll
    for (int q = 0; q < 4; ++q)
        fdv[q] = *(const float4*)(f_dst + bidx * N_ + q * 64 + l16 * 4);

    float4 ar[4][4];
    int rowg[4];
#pragma unroll
    for (int g = 0; g < 4; ++g) {
        rowg[g] = rowbase + wave * 16 + g * 4 + sub;
#pragma unroll
        for (int q = 0; q < 4; ++q)
            ar[g][q] = *(const float4*)(adj + (size_t)rowg[g] * N_ + q * 64 + l16 * 4);
    }
#pragma unroll
    for (int g = 0; g < 4; ++g) {
        float fs = f_src[rowg[g]];
        float p[16];
        float mx = -3.0e38f;
#pragma unroll
        for (int q = 0; q < 4; ++q) {
            float vv[4] = {fs + fdv[q].x, fs + fdv[q].y, fs + fdv[q].z, fs + fdv[q].w};
            float aa[4] = {ar[g][q].x, ar[g][q].y, ar[g][q].z, ar[g][q].w};
#pragma unroll
            for (int j = 0; j < 4; ++j) {
                float v = vv[j];
                v = v >= 0.f ? v : 0.2f * v;
                v = aa[j] > 0.f ? v : NEG_INF;
                p[q * 4 + j] = v;
                mx = fmaxf(mx, v);
            }
        }
#pragma unroll
        for (int off = 1; off < 16; off <<= 1) mx = fmaxf(mx, __shfl_xor(mx, off, 16));
        float s = 0.f;
#pragma unroll
        for (int j = 0; j < 16; ++j) { p[j] = __expf(p[j] - mx); s += p[j]; }
#pragma unroll
        for (int off = 1; off < 16; off <<= 1) s += __shfl_xor(s, off, 16);
        float inv = 1.0f / s;
        int lr = wave * 16 + g * 4 + sub;
#pragma unroll
        for (int q = 0; q < 4; ++q) {
            float4 o = make_float4(p[q*4]*inv, p[q*4+1]*inv, p[q*4+2]*inv, p[q*4+3]*inv);
            *(float4*)(att + (size_t)rowg[g] * N_ + q * 64 + l16 * 4) = o;
            *(f16x4*)&Al[lr * 264 + q * 64 + l16 * 4] =
                (f16x4){(f16)o.x, (f16)o.y, (f16)o.z, (f16)o.w};
        }
    }

    f32x4 acc[2][10];
#pragma unroll
    for (int rt = 0; rt < 2; ++rt)
#pragma unroll
        for (int i = 0; i < 10; ++i) acc[rt][i] = (f32x4){0.f, 0.f, 0.f, 0.f};

    __syncthreads();   // Al visible; DMA 0/1 drained

    // ---- phase 2: K-loop (K=256, BK=32) ----
#pragma unroll
    for (int kt = 0; kt < 8; ++kt) {
        const int cur = kt & 1;
        if (kt >= 1 && kt + 1 < 8) DMA_B2(cur ^ 1, kt + 1);

        f16x8 af0 = *(const f16x8*)&Al[(rh * 32 + c) * 264 + kt * 32 + quad * 8];
        f16x8 af1 = *(const f16x8*)&Al[(rh * 32 + 16 + c) * 264 + kt * 32 + quad * 8];
#pragma unroll
        for (int i = 0; i < 10; ++i) {
            int n = (chf * 10 + i) * 16 + c;
            f16x8 bf = *(const f16x8*)&Bl[cur][n * 32 + (quad ^ (n & 3)) * 8];
            acc[0][i] = __builtin_amdgcn_mfma_f32_16x16x32_f16(af0, bf, acc[0][i], 0, 0, 0);
            acc[1][i] = __builtin_amdgcn_mfma_f32_16x16x32_f16(af1, bf, acc[1][i], 0, 0, 0);
        }
        __syncthreads();
    }

    // ---- epilogue: hp[row][col], col<300 ----
#pragma unroll
    for (int i = 0; i < 10; ++i) {
        int col = (chf * 10 + i) * 16 + c;
        if (col < DOUT) {
#pragma unroll
            for (int rt = 0; rt < 2; ++rt) {
                int row0 = rowbase + rh * 32 + rt * 16 + quad * 4;
#pragma unroll
                for (int r = 0; r < 4; ++r)
                    hp[(size_t)(row0 + r) * DOUT + col] = acc[rt][i][r];
            }
        }
    }
#undef DMA_B2
}

extern "C" void kernel_launch(void* const* d_in, const int* in_sizes, int n_in,
                              void* d_out, int out_size, void* d_ws, size_t ws_size,
                              hipStream_t stream)
{
    const float* h         = (const float*)d_in[0];
    const float* adj       = (const float*)d_in[1];
    const int*   positions = (const int*)d_in[2];
    const float* W         = (const float*)d_in[3];
    const float* a_src     = (const float*)d_in[4];
    const float* a_dst     = (const float*)d_in[5];
    const float* pos_table = (const float*)d_in[6];

    float* hp  = (float*)d_out;            // [65536][300]
    float* att = hp + HP_ELEMS;            // [65536][256]

    f16*   Wt    = (f16*)d_ws;                         // 320*768
    f16*   WhT   = Wt + (size_t)DOUTP * DIN;           // 256*320*256
    float* f_src = (float*)(WhT + (size_t)B_ * DOUTP * N_);
    float* f_dst = f_src + M_;

    hipLaunchKernelGGL(prep_wt, dim3((DOUTP * DIN + 255) / 256), dim3(256), 0, stream, W, Wt);
    hipLaunchKernelGGL(gemm1,   dim3(M_ / 64), dim3(256), 0, stream,
                       h, Wt, positions, a_src, a_dst, pos_table, WhT, f_src, f_dst);
    hipLaunchKernelGGL(gemm2,   dim3(M_ / 64), dim3(256), 0, stream,
                       adj, f_src, f_dst, WhT, att, hp);
}